// Round 1
// baseline (517.713 us; speedup 1.0000x reference)
//
#include <hip/hip_runtime.h>

#define TPB   256
#define TT    28          // t-windows per block
#define SEG   155         // TT*5 + 15 segment positions
#define NF    32
#define T_TOT 406
#define LLEN  2048
#define NPAIR 496
#define FSW   36          // padded feature stride (multiple of 4 for b128 align)

__device__ __forceinline__ unsigned short f2bf(float f) {
    unsigned int u = __float_as_uint(f);
    u += 0x7fffu + ((u >> 16) & 1u);           // RNE
    return (unsigned short)(u >> 16);
}

__global__ __launch_bounds__(TPB, 2)
void tscorr_kernel(const float* __restrict__ x, float* __restrict__ out) {
    __shared__ float          fs[SEG * FSW];      // 22320 B, feature-major, swizzled
    __shared__ float2         st[NF * TT];        //  7168 B, (mu, norm) per (f, tloc)
    __shared__ unsigned short ot[NPAIR * TT];     // 27776 B, bf16 out tile

    const int tid   = threadIdx.x;
    const int chunk = blockIdx.x;
    const int b     = blockIdx.y;
    const int t0    = chunk * TT;
    const int l0    = t0 * 5;
    const float* xb = x + (size_t)b * NF * LLEN;

    // ---------------- Phase A: load segment, transpose + XOR swizzle ----------------
    for (int idx = tid; idx < NF * SEG; idx += TPB) {
        int f   = idx / SEG;
        int pos = idx - f * SEG;
        int lg  = l0 + pos;
        float v = (lg < LLEN) ? xb[f * LLEN + lg] : 0.0f;
        int sw  = ((pos ^ (pos >> 3)) & 7) << 2;
        fs[pos * FSW + (f ^ sw)] = v;
    }
    __syncthreads();

    int pb = 0, tl = 0, bi = 0, bj = 0, t0loc = 0;
    float A[4][4][4];
    const bool active = (tid < 252);
    if (active) {
        pb = tid / 7;
        tl = tid - pb * 7;
        int rem = pb;
        while (rem >= 8 - bi) { rem -= 8 - bi; ++bi; }
        bj = bi + rem;
        t0loc = tl * 4;

        // ---------------- Phase C1: chunk-Gram accumulation ----------------
        #pragma unroll
        for (int t = 0; t < 4; ++t)
            #pragma unroll
            for (int r = 0; r < 4; ++r)
                #pragma unroll
                for (int c = 0; c < 4; ++c) A[t][r][c] = 0.f;

        float S[4][4];            // row sums (diagonal blocks only)
        const bool diag = (bi == bj);
        #pragma unroll
        for (int t = 0; t < 4; ++t)
            #pragma unroll
            for (int r = 0; r < 4; ++r) S[t][r] = 0.f;

        const int lbase = t0loc * 5;
        #pragma unroll
        for (int u = 0; u < 7; ++u) {
            float q[4][4];
            float cs[4];
            #pragma unroll
            for (int r = 0; r < 4; ++r) {
                cs[r] = 0.f;
                #pragma unroll
                for (int c = 0; c < 4; ++c) q[r][c] = 0.f;
            }
            #pragma unroll
            for (int d = 0; d < 5; ++d) {
                int l  = lbase + u * 5 + d;
                int sw = ((l ^ (l >> 3)) & 7) << 2;
                const float4 vi = *(const float4*)&fs[l * FSW + ((bi * 4) ^ sw)];
                const float4 vj = *(const float4*)&fs[l * FSW + ((bj * 4) ^ sw)];
                float xi[4] = {vi.x, vi.y, vi.z, vi.w};
                float xj[4] = {vj.x, vj.y, vj.z, vj.w};
                #pragma unroll
                for (int r = 0; r < 4; ++r) {
                    #pragma unroll
                    for (int c = 0; c < 4; ++c)
                        q[r][c] = fmaf(xi[r], xj[c], q[r][c]);
                }
                if (diag) {
                    #pragma unroll
                    for (int r = 0; r < 4; ++r) cs[r] += xi[r];
                }
            }
            #pragma unroll
            for (int t = 0; t < 4; ++t) {
                if (u >= t && u <= t + 3) {     // compile-time after unroll
                    #pragma unroll
                    for (int r = 0; r < 4; ++r) {
                        #pragma unroll
                        for (int c = 0; c < 4; ++c) A[t][r][c] += q[r][c];
                        if (diag) S[t][r] += cs[r];
                    }
                }
            }
        }

        // diagonal blocks publish stats: mu, n = sqrt(G_ff - 20 mu^2)
        if (diag) {
            #pragma unroll
            for (int r = 0; r < 4; ++r) {
                #pragma unroll
                for (int t = 0; t < 4; ++t) {
                    float mu = S[t][r] * 0.05f;
                    float n2 = A[t][r][r] - 20.f * mu * mu;
                    st[(bi * 4 + r) * TT + t0loc + t] =
                        make_float2(mu, sqrtf(fmaxf(n2, 0.f)));
                }
            }
        }
    }
    __syncthreads();

    // ---------------- Phase C2: correction + bf16 staging ----------------
    if (active) {
        float2 si[4][4], sj[4][4];           // [row][t]
        #pragma unroll
        for (int r = 0; r < 4; ++r) {
            const float2* pi = &st[(bi * 4 + r) * TT + t0loc];
            const float2* pj = &st[(bj * 4 + r) * TT + t0loc];
            #pragma unroll
            for (int t = 0; t < 4; ++t) { si[r][t] = pi[t]; sj[r][t] = pj[t]; }
        }
        const int nvalid = T_TOT - (t0 + t0loc);
        const bool all4  = (nvalid >= 4);
        #pragma unroll
        for (int r = 0; r < 4; ++r) {
            int fi = bi * 4 + r;
            #pragma unroll
            for (int c = 0; c < 4; ++c) {
                int fj = bj * 4 + c;
                if (fj > fi) {                            // compile-time except diag blocks
                    int p = fi * (63 - fi) / 2 + (fj - fi - 1);
                    unsigned short bf[4];
                    #pragma unroll
                    for (int t = 0; t < 4; ++t) {
                        float num = A[t][r][c] - 20.f * si[r][t].x * sj[c][t].x;
                        float den = si[r][t].y * sj[c][t].y + 1e-8f;
                        bf[t] = f2bf(num * __builtin_amdgcn_rcpf(den));
                    }
                    if (all4) {
                        uint2 w;
                        w.x = (unsigned)bf[0] | ((unsigned)bf[1] << 16);
                        w.y = (unsigned)bf[2] | ((unsigned)bf[3] << 16);
                        *(uint2*)&ot[p * TT + t0loc] = w;   // 8B aligned
                    } else {
                        #pragma unroll
                        for (int t = 0; t < 4; ++t)
                            if (t < nvalid) ot[p * TT + t0loc + t] = bf[t];
                    }
                }
            }
        }
    }
    __syncthreads();

    // ---------------- Phase D: coalesced write-out (bf16 -> f32) ----------------
    for (int k = tid; k < NPAIR * (TT / 2); k += TPB) {
        int p  = k / (TT / 2);
        int tp = k - p * (TT / 2);
        int t  = t0 + tp * 2;
        if (t < T_TOT) {
            unsigned int v = *(const unsigned int*)&ot[p * TT + tp * 2];
            float2 o;
            o.x = __uint_as_float((v & 0xffffu) << 16);
            o.y = __uint_as_float(v & 0xffff0000u);
            *(float2*)&out[((size_t)b * NPAIR + p) * T_TOT + t] = o;  // 8B aligned (406 even)
        }
    }
}

extern "C" void kernel_launch(void* const* d_in, const int* in_sizes, int n_in,
                              void* d_out, int out_size, void* d_ws, size_t ws_size,
                              hipStream_t stream) {
    const float* x = (const float*)d_in[0];
    float* out     = (float*)d_out;
    dim3 grid(15, 256);      // 15 t-chunks x 256 batches
    hipLaunchKernelGGL(tscorr_kernel, grid, dim3(TPB), 0, stream, x, out);
}